// Round 7
// baseline (667.202 us; speedup 1.0000x reference)
//
#include <hip/hip_runtime.h>
#include <hip/hip_bf16.h>

// Swin block fused: C=180, NH=6, HD=30, WS=8, SS=4, N=64, B=16, H=W=128.
typedef short s16x8 __attribute__((ext_vector_type(8)));
typedef short s16x4 __attribute__((ext_vector_type(4)));
typedef float f32x4 __attribute__((ext_vector_type(4)));

__device__ __forceinline__ short f2bf(float f) {
    __bf16 h = (__bf16)f;
    return __builtin_bit_cast(short, h);
}
__device__ __forceinline__ float bf2f(short s) {
    return __builtin_bit_cast(float, ((unsigned int)(unsigned short)s) << 16);
}
__device__ __forceinline__ f32x4 mfma16(s16x8 a, s16x8 b, f32x4 c) {
    return __builtin_amdgcn_mfma_f32_16x16x32_bf16(a, b, c, 0, 0, 0);
}
// 8-byte-aligned b128 substitute (two ds_read_b64) for stride-36 rows
__device__ __forceinline__ s16x8 ld_b64x2(const short* p) {
    union { s16x8 v; s16x4 h[2]; } u;
    u.h[0] = *(const s16x4*)p;
    u.h[1] = *(const s16x4*)(p + 4);
    return u.v;
}

#define SCALE_Q 0.18257418583505536f

// ---------------- workspace layout (bytes) ----------------
// Whead bf16 [6][96][192] @ 0       rows: 0-31 q(scaled), 32-63 k, 64-95 v (hd pad 32)
// Wproj bf16 [192][192]   @ 221184
// Wfc1  bf16 [384][192]   @ 294912
// Wfc2  bf16 [192][384]   @ 442368
// battn bf16 [6][64(m)][64(n)] @ 589824  (TRANSPOSED: m-major)
// bh    f32  [6][96]      @ 638976
// bfc1  f32  [384]        @ 641280   total 642816

__global__ void k_prep(const float* __restrict__ qkv_w, const float* __restrict__ qkv_b,
                       const float* __restrict__ proj_w,
                       const float* __restrict__ fc1_w, const float* __restrict__ fc1_b,
                       const float* __restrict__ fc2_w,
                       const float* __restrict__ rpb,
                       short* __restrict__ Whead, short* __restrict__ Wproj,
                       short* __restrict__ Wfc1, short* __restrict__ Wfc2,
                       short* __restrict__ battn, float* __restrict__ bh,
                       float* __restrict__ bfc1) {
    int gt = blockIdx.x * 256 + threadIdx.x;
    int stride = gridDim.x * 256;
    for (int idx = gt; idx < 6 * 96 * 192; idx += stride) {
        int h = idx / (96 * 192), rem = idx - h * 96 * 192;
        int rr = rem / 192, kk = rem - rr * 192;
        int seg = rr >> 5, hd = rr & 31;
        float val = 0.f;
        if (hd < 30 && kk < 180) {
            int ch = seg * 180 + h * 30 + hd;
            val = qkv_w[ch * 180 + kk];
            if (seg == 0) val *= SCALE_Q;
        }
        Whead[idx] = f2bf(val);
    }
    for (int idx = gt; idx < 6 * 96; idx += stride) {
        int h = idx / 96, rr = idx - h * 96;
        int seg = rr >> 5, hd = rr & 31;
        float val = 0.f;
        if (hd < 30) {
            int ch = seg * 180 + h * 30 + hd;
            val = qkv_b[ch];
            if (seg == 0) val *= SCALE_Q;
        }
        bh[idx] = val;
    }
    for (int idx = gt; idx < 192 * 192; idx += stride) {
        int rr = idx / 192, kk = idx - rr * 192;
        Wproj[idx] = (rr < 180 && kk < 180) ? f2bf(proj_w[rr * 180 + kk]) : (short)0;
    }
    for (int idx = gt; idx < 384 * 192; idx += stride) {
        int rr = idx / 192, kk = idx - rr * 192;
        Wfc1[idx] = (rr < 360 && kk < 180) ? f2bf(fc1_w[rr * 180 + kk]) : (short)0;
    }
    for (int idx = gt; idx < 384; idx += stride)
        bfc1[idx] = (idx < 360) ? fc1_b[idx] : 0.f;
    for (int idx = gt; idx < 192 * 384; idx += stride) {
        int rr = idx / 384, kk = idx - rr * 384;
        Wfc2[idx] = (rr < 180 && kk < 360) ? f2bf(fc2_w[rr * 360 + kk]) : (short)0;
    }
    // battn[h][m][n] = bias[h][n][m]  (bf16, transposed so n is contiguous)
    for (int idx = gt; idx < 6 * 64 * 64; idx += stride) {
        int h = idx >> 12, m = (idx >> 6) & 63, n = idx & 63;
        int r1 = n >> 3, c1 = n & 7, r2 = m >> 3, c2 = m & 7;
        int ridx = (r1 - r2 + 7) * 15 + (c1 - c2 + 7);
        battn[idx] = f2bf(rpb[ridx * 6 + h]);
    }
}

// ---------------- fully fused kernel ----------------
// 1 block/window, 384 thr = 6 waves, wave h owns head h.
// LDS 53248 B -> 3 WG/CU; VGPR must stay <= ~102 for 5 wave-slots/SIMD.
// __launch_bounds__ 2nd arg maps to VGPR cap ~256/w (measured R1/R3/R6):
// w=2 -> cap 128 -> natural ~90-100 alloc, NO SPILLS (w=5 capped at 48 and
// spilled ~600 MB of scratch to HBM in R6).
//  region A @0     (25600): xln[64][200] -> xout[64][200] -> ylds[64][200] -> mo bf16
//  region B @25600 (27648): patches 6x4608 -> pout bf16 [64][200] -> hid bf16 [64][200]
__global__ __launch_bounds__(384, 2)
void k_fused(const float* __restrict__ x, const float* __restrict__ g1, const float* __restrict__ b1,
             const short* __restrict__ Whead, const float* __restrict__ bh,
             const short* __restrict__ Wproj, const float* __restrict__ projb,
             const short* __restrict__ battn,
             const float* __restrict__ g2, const float* __restrict__ b2,
             const short* __restrict__ Wfc1, const float* __restrict__ bfc1,
             const short* __restrict__ Wfc2, const float* __restrict__ fb2,
             float* __restrict__ out) {
    __shared__ __align__(16) char smem[53248];
    short* xln  = (short*)smem;               // [64][200]
    short* xout = (short*)smem;               // overlays xln (after staging done)
    short* ylds = (short*)smem;               // overlays xout (after proj A-reads)
    short* mo   = (short*)smem;               // overlays ylds (after fc1 done)
    short* regB = (short*)(smem + 25600);
    short* pout = regB;                       // bf16 [64][200]
    short* hid  = regB;                       // bf16 [64][200]

    const int tid = threadIdx.x;
    const int wv = tid >> 6, l = tid & 63, l15 = l & 15, lg = l >> 4;
    short* patch = regB + wv * 2304;          // 4608 B each
    const int wid = blockIdx.x;
    const int b = wid >> 8, win = wid & 255, wi = win >> 4, wj = win & 15;
    const bool edge = (wi == 15) || (wj == 15);
    const f32x4 vzero = {0.f, 0.f, 0.f, 0.f};

    const int t = tid >> 2, sub = tid & 3;
    size_t rowbase = 0;
    if (tid < 256) {
        const int r = t >> 3, c = t & 7;
        const int gi = (wi * 8 + r + 4) & 127, gj = (wj * 8 + c + 4) & 127;
        rowbase = ((size_t)b * 16384 + (size_t)gi * 128 + gj) * 180;
    }
    const float* xrow = x + rowbase;
    float* yrow = out + rowbase;

    // ---- P1: LN1 -> xln (waves 0-3); helpers zero xln pads ----
    if (tid < 256) {
        float4 v[12];
        float s1 = 0.f, s2 = 0.f;
#pragma unroll
        for (int m = 0; m < 12; ++m) {
            int jj = sub + 4 * m;
            if (jj < 45) {
                float4 t4 = *(const float4*)&xrow[4 * jj];
                v[m] = t4;
                s1 += t4.x + t4.y + t4.z + t4.w;
                s2 += t4.x * t4.x + t4.y * t4.y + t4.z * t4.z + t4.w * t4.w;
            }
        }
        s1 += __shfl_xor(s1, 1); s2 += __shfl_xor(s2, 1);
        s1 += __shfl_xor(s1, 2); s2 += __shfl_xor(s2, 2);
        const float mu = s1 * (1.f / 180.f);
        const float rstd = rsqrtf(s2 * (1.f / 180.f) - mu * mu + 1e-5f);
#pragma unroll
        for (int m = 0; m < 12; ++m) {
            int jj = sub + 4 * m;
            if (jj < 45) {
                float4 g4 = *(const float4*)&g1[4 * jj];
                float4 b4 = *(const float4*)&b1[4 * jj];
                s16x4 w;
                w[0] = f2bf((v[m].x - mu) * rstd * g4.x + b4.x);
                w[1] = f2bf((v[m].y - mu) * rstd * g4.y + b4.y);
                w[2] = f2bf((v[m].z - mu) * rstd * g4.z + b4.z);
                w[3] = f2bf((v[m].w - mu) * rstd * g4.w + b4.w);
                *(s16x4*)&xln[t * 200 + 4 * jj] = w;
            }
        }
    } else {
        for (int k = tid - 256; k < 64 * 12; k += 128) {
            int rr = k / 12, cc = k - rr * 12;
            xln[rr * 200 + 180 + cc] = 0;
        }
    }
    __syncthreads();   // B1: xln ready

    // ---- P2: per-wave head staging (Q,K,V through private patch) ----
    const short* Wh = Whead + wv * (96 * 192);
    const float* bhh = bh + wv * 96;

    auto stage = [&](int G, auto&& store) {
#pragma unroll
        for (int jl = 0; jl < 2; ++jl) {
            s16x8 bw[6];
#pragma unroll
            for (int ks = 0; ks < 6; ++ks)
                bw[ks] = *(const s16x8*)&Wh[(G * 32 + jl * 16 + l15) * 192 + ks * 32 + lg * 8];
            float bias = bhh[G * 32 + jl * 16 + l15];
#pragma unroll
            for (int i = 0; i < 4; ++i) {
                f32x4 acc = vzero;
#pragma unroll
                for (int ks = 0; ks < 6; ++ks) {
                    s16x8 afi = *(const s16x8*)&xln[(i * 16 + l15) * 200 + ks * 32 + lg * 8];
                    acc = mfma16(afi, bw[ks], acc);
                }
                store(i, jl, acc, bias);
            }
        }
    };

    // Q -> patch [64][36]
    stage(0, [&](int i, int jl, f32x4 acc, float bias) {
#pragma unroll
        for (int tt = 0; tt < 4; ++tt)
            patch[(i * 16 + lg * 4 + tt) * 36 + jl * 16 + l15] = f2bf(acc[tt] + bias);
    });
    s16x8 qf[4];
#pragma unroll
    for (int i = 0; i < 4; ++i) qf[i] = ld_b64x2(&patch[(i * 16 + l15) * 36 + lg * 8]);

    // K -> patch [64][36] (reuse)
    stage(1, [&](int i, int jl, f32x4 acc, float bias) {
#pragma unroll
        for (int tt = 0; tt < 4; ++tt)
            patch[(i * 16 + lg * 4 + tt) * 36 + jl * 16 + l15] = f2bf(acc[tt] + bias);
    });
    s16x8 kf[4];
#pragma unroll
    for (int j = 0; j < 4; ++j) kf[j] = ld_b64x2(&patch[(j * 16 + l15) * 36 + lg * 8]);

    // V -> patch transposed [32][72], packed u32 stores
    stage(2, [&](int i, int jl, f32x4 acc, float bias) {
        int hd = jl * 16 + l15;
        int tok0 = i * 16 + lg * 4;
        unsigned int w0 = (unsigned int)(unsigned short)f2bf(acc[0] + bias) |
                          ((unsigned int)(unsigned short)f2bf(acc[1] + bias) << 16);
        unsigned int w1 = (unsigned int)(unsigned short)f2bf(acc[2] + bias) |
                          ((unsigned int)(unsigned short)f2bf(acc[3] + bias) << 16);
        *(unsigned int*)&patch[hd * 72 + tok0] = w0;
        *(unsigned int*)&patch[hd * 72 + tok0 + 2] = w1;
    });
    s16x8 vf[2][2];
#pragma unroll
    for (int j2 = 0; j2 < 2; ++j2)
#pragma unroll
        for (int ksv = 0; ksv < 2; ++ksv)
            vf[j2][ksv] = *(const s16x8*)&patch[(j2 * 16 + l15) * 72 + ksv * 32 + lg * 8];

    __syncthreads();   // B_x: all xln reads done -> xout (region A) writable

    if (wv == 0) {     // zero xout pad cols 180..191
        for (int k = l; k < 64 * 12; k += 64) {
            int rr = k / 12, cc = k - rr * 12;
            xout[rr * 200 + 180 + cc] = 0;
        }
    }

    // ---- attention: scores + softmax + PV, P ping-pong in patch ----
    {
        const short* bb = battn + wv * 4096;
#pragma unroll
        for (int i = 0; i < 4; ++i) {
            f32x4 sc[4];
#pragma unroll
            for (int j = 0; j < 4; ++j) sc[j] = mfma16(qf[i], kf[j], vzero);
            float p[4][4];
#pragma unroll
            for (int j = 0; j < 4; ++j) {
                int m = j * 16 + l15;
                s16x4 bv = *(const s16x4*)&bb[m * 64 + i * 16 + lg * 4];
                int rm = m >> 3, cm = m & 7;
                int cnt_m = (wi == 15 ? ((rm >= 4) ? 2 : 1) : 0) * 3 + (wj == 15 ? ((cm >= 4) ? 2 : 1) : 0);
#pragma unroll
                for (int tt = 0; tt < 4; ++tt) {
                    int n = i * 16 + lg * 4 + tt;
                    float s = sc[j][tt] + bf2f(bv[tt]);
                    if (edge) {
                        int rn = n >> 3, cn = n & 7;
                        int cnt_n = (wi == 15 ? ((rn >= 4) ? 2 : 1) : 0) * 3 + (wj == 15 ? ((cn >= 4) ? 2 : 1) : 0);
                        if (cnt_n != cnt_m) s -= 100.f;
                    }
                    p[j][tt] = s;
                }
            }
            float sm[4];
#pragma unroll
            for (int tt = 0; tt < 4; ++tt) {
                float m0 = fmaxf(fmaxf(p[0][tt], p[1][tt]), fmaxf(p[2][tt], p[3][tt]));
                m0 = fmaxf(m0, __shfl_xor(m0, 1));
                m0 = fmaxf(m0, __shfl_xor(m0, 2));
                m0 = fmaxf(m0, __shfl_xor(m0, 4));
                m0 = fmaxf(m0, __shfl_xor(m0, 8));
                float s0 = 0.f;
#pragma unroll
                for (int j = 0; j < 4; ++j) { float e = __expf(p[j][tt] - m0); p[j][tt] = e; s0 += e; }
                s0 += __shfl_xor(s0, 1); s0 += __shfl_xor(s0, 2);
                s0 += __shfl_xor(s0, 4); s0 += __shfl_xor(s0, 8);
                sm[tt] = __builtin_amdgcn_rcpf(s0);
            }
            short* pb = patch + (i & 1) * 1152;   // ping-pong [16][72]
#pragma unroll
            for (int j = 0; j < 4; ++j)
#pragma unroll
                for (int tt = 0; tt < 4; ++tt)
                    pb[(lg * 4 + tt) * 72 + j * 16 + l15] = f2bf(p[j][tt] * sm[tt]);
            s16x8 pa0 = *(const s16x8*)&pb[l15 * 72 + lg * 8];
            s16x8 pa1 = *(const s16x8*)&pb[l15 * 72 + 32 + lg * 8];
            f32x4 ov0 = mfma16(pa0, vf[0][0], vzero);
            ov0 = mfma16(pa1, vf[0][1], ov0);
            f32x4 ov1 = mfma16(pa0, vf[1][0], vzero);
            ov1 = mfma16(pa1, vf[1][1], ov1);
            // xout rows i*16.., cols wv*30 + hd
#pragma unroll
            for (int tt = 0; tt < 4; ++tt)
                xout[(i * 16 + lg * 4 + tt) * 200 + wv * 30 + l15] = f2bf(ov0[tt]);
            if (l15 < 14) {
#pragma unroll
                for (int tt = 0; tt < 4; ++tt)
                    xout[(i * 16 + lg * 4 + tt) * 200 + wv * 30 + 16 + l15] = f2bf(ov1[tt]);
            }
        }
    }
    __syncthreads();   // B3: xout complete, patches dead

    // ---- P3: proj GEMM -> pout bf16 (region B) ----
    {
#pragma unroll
        for (int jl = 0; jl < 2; ++jl) {
            s16x8 bw[6];
#pragma unroll
            for (int ks = 0; ks < 6; ++ks)
                bw[ks] = *(const s16x8*)&Wproj[(wv * 32 + jl * 16 + l15) * 192 + ks * 32 + lg * 8];
            int cch = wv * 32 + jl * 16 + l15;
            float pbv = (cch < 180) ? projb[cch] : 0.f;
#pragma unroll
            for (int i = 0; i < 4; ++i) {
                f32x4 acc = vzero;
#pragma unroll
                for (int ks = 0; ks < 6; ++ks) {
                    s16x8 afi = *(const s16x8*)&xout[(i * 16 + l15) * 200 + ks * 32 + lg * 8];
                    acc = mfma16(afi, bw[ks], acc);
                }
                if (cch < 180) {
#pragma unroll
                    for (int tt = 0; tt < 4; ++tt)
                        pout[(i * 16 + lg * 4 + tt) * 200 + cch] = f2bf(acc[tt] + pbv);
                }
            }
        }
    }
    __syncthreads();   // B4: pout ready, xout dead

    // ---- P4: y = x + pout -> d_out (f32) ; LN2 -> ylds ----
    if (tid < 256) {
        float4 yv[12];
        float s1 = 0.f, s2 = 0.f;
#pragma unroll
        for (int m = 0; m < 12; ++m) {
            int jj = sub + 4 * m;
            if (jj < 45) {
                float4 x4 = *(const float4*)&xrow[4 * jj];
                s16x4 pv = *(const s16x4*)&pout[t * 200 + 4 * jj];
                float4 y4;
                y4.x = x4.x + bf2f(pv[0]); y4.y = x4.y + bf2f(pv[1]);
                y4.z = x4.z + bf2f(pv[2]); y4.w = x4.w + bf2f(pv[3]);
                yv[m] = y4;
                *(float4*)&yrow[4 * jj] = y4;
                s1 += y4.x + y4.y + y4.z + y4.w;
                s2 += y4.x * y4.x + y4.y * y4.y + y4.z * y4.z + y4.w * y4.w;
            }
        }
        s1 += __shfl_xor(s1, 1); s2 += __shfl_xor(s2, 1);
        s1 += __shfl_xor(s1, 2); s2 += __shfl_xor(s2, 2);
        const float mu = s1 * (1.f / 180.f);
        const float rstd = rsqrtf(s2 * (1.f / 180.f) - mu * mu + 1e-5f);
#pragma unroll
        for (int m = 0; m < 12; ++m) {
            int jj = sub + 4 * m;
            if (jj < 45) {
                float4 g4 = *(const float4*)&g2[4 * jj];
                float4 b4 = *(const float4*)&b2[4 * jj];
                s16x4 w;
                w[0] = f2bf((yv[m].x - mu) * rstd * g4.x + b4.x);
                w[1] = f2bf((yv[m].y - mu) * rstd * g4.y + b4.y);
                w[2] = f2bf((yv[m].z - mu) * rstd * g4.z + b4.z);
                w[3] = f2bf((yv[m].w - mu) * rstd * g4.w + b4.w);
                *(s16x4*)&ylds[t * 200 + 4 * jj] = w;
            }
        }
    } else {
        for (int k = tid - 256; k < 64 * 12; k += 128) {
            int rr = k / 12, cc = k - rr * 12;
            ylds[rr * 200 + 180 + cc] = 0;
        }
    }
    __syncthreads();   // B5: ylds ready, pout dead

    // ---- P5: MLP (fc1+GELU per K-half, fc2 accumulated) ----
    f32x4 acc3[2][4];
#pragma unroll
    for (int jl = 0; jl < 2; ++jl)
#pragma unroll
        for (int i = 0; i < 4; ++i) acc3[jl][i] = vzero;

#pragma unroll
    for (int kh = 0; kh < 2; ++kh) {
#pragma unroll
        for (int jl = 0; jl < 2; ++jl) {
            s16x8 bw[6];
#pragma unroll
            for (int ks = 0; ks < 6; ++ks)
                bw[ks] = *(const s16x8*)&Wfc1[((kh * 12 + wv * 2 + jl) * 16 + l15) * 192 + ks * 32 + lg * 8];
            int cl = (wv * 2 + jl) * 16 + l15;
            float bv = bfc1[kh * 192 + cl];
#pragma unroll
            for (int i = 0; i < 4; ++i) {
                f32x4 acc = vzero;
#pragma unroll
                for (int ks = 0; ks < 6; ++ks) {
                    s16x8 ai = *(const s16x8*)&ylds[(i * 16 + l15) * 200 + ks * 32 + lg * 8];
                    acc = mfma16(ai, bw[ks], acc);
                }
#pragma unroll
                for (int tt = 0; tt < 4; ++tt) {
                    float v = acc[tt] + bv;
                    // gelu(v) ~= v * sigmoid(1.5957691*(v + 0.044715 v^3)); max err ~3e-4
                    float u = v * (1.f + 0.044715f * v * v);
                    float e = __expf(-1.5957691216f * u);
                    float gl = v * __builtin_amdgcn_rcpf(1.f + e);
                    hid[(i * 16 + lg * 4 + tt) * 200 + cl] = f2bf(gl);
                }
            }
        }
        __syncthreads();   // hid(kh) ready
#pragma unroll
        for (int ks = 0; ks < 6; ++ks) {
            s16x8 a[4];
#pragma unroll
            for (int i = 0; i < 4; ++i)
                a[i] = *(const s16x8*)&hid[(i * 16 + l15) * 200 + ks * 32 + lg * 8];
#pragma unroll
            for (int jl = 0; jl < 2; ++jl) {
                s16x8 bw2 = *(const s16x8*)&Wfc2[((wv * 2 + jl) * 16 + l15) * 384 + kh * 192 + ks * 32 + lg * 8];
#pragma unroll
                for (int i = 0; i < 4; ++i) acc3[jl][i] = mfma16(a[i], bw2, acc3[jl][i]);
            }
        }
        __syncthreads();   // hid consumed
    }

    // ---- fc2 out -> mo bf16 (region A; ylds dead) ----
#pragma unroll
    for (int jl = 0; jl < 2; ++jl) {
        int cch = (wv * 2 + jl) * 16 + l15;
        if (cch < 180) {
            float bv = fb2[cch];
#pragma unroll
            for (int i = 0; i < 4; ++i)
#pragma unroll
                for (int tt = 0; tt < 4; ++tt)
                    mo[(i * 16 + lg * 4 + tt) * 200 + cch] = f2bf(acc3[jl][i][tt] + bv);
        }
    }
    __syncthreads();   // B6: mo ready

    // ---- final: out = y + mlp ----
    if (tid < 256) {
#pragma unroll
        for (int m = 0; m < 12; ++m) {
            int jj = sub + 4 * m;
            if (jj < 45) {
                float4 y4 = *(const float4*)&yrow[4 * jj];
                s16x4 mv = *(const s16x4*)&mo[t * 200 + 4 * jj];
                float4 o;
                o.x = y4.x + bf2f(mv[0]); o.y = y4.y + bf2f(mv[1]);
                o.z = y4.z + bf2f(mv[2]); o.w = y4.w + bf2f(mv[3]);
                *(float4*)&yrow[4 * jj] = o;
            }
        }
    }
}

extern "C" void kernel_launch(void* const* d_in, const int* in_sizes, int n_in,
                              void* d_out, int out_size, void* d_ws, size_t ws_size,
                              hipStream_t stream) {
    (void)in_sizes; (void)n_in; (void)out_size; (void)ws_size;
    const float* x      = (const float*)d_in[0];
    const float* ln1g   = (const float*)d_in[1];
    const float* ln1b   = (const float*)d_in[2];
    const float* qkv_w  = (const float*)d_in[3];
    const float* qkv_b  = (const float*)d_in[4];
    const float* proj_w = (const float*)d_in[5];
    const float* proj_b = (const float*)d_in[6];
    const float* rpb    = (const float*)d_in[7];
    const float* ln2g   = (const float*)d_in[8];
    const float* ln2b   = (const float*)d_in[9];
    const float* fc1_w  = (const float*)d_in[10];
    const float* fc1_b  = (const float*)d_in[11];
    const float* fc2_w  = (const float*)d_in[12];
    const float* fc2_b  = (const float*)d_in[13];
    float* out = (float*)d_out;

    char* ws = (char*)d_ws;
    short* Whead = (short*)(ws + 0);
    short* Wproj = (short*)(ws + 221184);
    short* Wfc1  = (short*)(ws + 294912);
    short* Wfc2  = (short*)(ws + 442368);
    short* battn = (short*)(ws + 589824);
    float* bhp   = (float*)(ws + 638976);
    float* bfc1p = (float*)(ws + 641280);

    k_prep<<<256, 256, 0, stream>>>(qkv_w, qkv_b, proj_w, fc1_w, fc1_b, fc2_w, rpb,
                                    Whead, Wproj, Wfc1, Wfc2, battn, bhp, bfc1p);
    k_fused<<<4096, 384, 0, stream>>>(x, ln1g, ln1b, Whead, bhp, Wproj, proj_b, battn,
                                      ln2g, ln2b, Wfc1, bfc1p, Wfc2, fc2_b, out);
}

// Round 8
// 593.102 us; speedup vs baseline: 1.1249x; 1.1249x over previous
//
#include <hip/hip_runtime.h>
#include <hip/hip_bf16.h>

// Swin block fused: C=180, NH=6, HD=30, WS=8, SS=4, N=64, B=16, H=W=128.
typedef short s16x8 __attribute__((ext_vector_type(8)));
typedef short s16x4 __attribute__((ext_vector_type(4)));
typedef float f32x4 __attribute__((ext_vector_type(4)));

__device__ __forceinline__ short f2bf(float f) {
    __bf16 h = (__bf16)f;
    return __builtin_bit_cast(short, h);
}
__device__ __forceinline__ float bf2f(short s) {
    return __builtin_bit_cast(float, ((unsigned int)(unsigned short)s) << 16);
}
__device__ __forceinline__ f32x4 mfma16(s16x8 a, s16x8 b, f32x4 c) {
    return __builtin_amdgcn_mfma_f32_16x16x32_bf16(a, b, c, 0, 0, 0);
}
// 8-byte-aligned b128 substitute (two ds_read_b64) for stride-36 rows
__device__ __forceinline__ s16x8 ld_b64x2(const short* p) {
    union { s16x8 v; s16x4 h[2]; } u;
    u.h[0] = *(const s16x4*)p;
    u.h[1] = *(const s16x4*)(p + 4);
    return u.v;
}

#define SCALE_Q 0.18257418583505536f

// ---------------- workspace layout (bytes) ----------------
// Whead bf16 [6][96][192] @ 0       rows: 0-31 q(scaled), 32-63 k, 64-95 v (hd pad 32)
// Wproj bf16 [192][192]   @ 221184
// Wfc1  bf16 [384][192]   @ 294912
// Wfc2  bf16 [192][384]   @ 442368
// battn bf16 [6][64(m)][64(n)] @ 589824  (TRANSPOSED: m-major)
// bh    f32  [6][96]      @ 638976
// bfc1  f32  [384]        @ 641280   total 642816

__global__ void k_prep(const float* __restrict__ qkv_w, const float* __restrict__ qkv_b,
                       const float* __restrict__ proj_w,
                       const float* __restrict__ fc1_w, const float* __restrict__ fc1_b,
                       const float* __restrict__ fc2_w,
                       const float* __restrict__ rpb,
                       short* __restrict__ Whead, short* __restrict__ Wproj,
                       short* __restrict__ Wfc1, short* __restrict__ Wfc2,
                       short* __restrict__ battn, float* __restrict__ bh,
                       float* __restrict__ bfc1) {
    int gt = blockIdx.x * 256 + threadIdx.x;
    int stride = gridDim.x * 256;
    for (int idx = gt; idx < 6 * 96 * 192; idx += stride) {
        int h = idx / (96 * 192), rem = idx - h * 96 * 192;
        int rr = rem / 192, kk = rem - rr * 192;
        int seg = rr >> 5, hd = rr & 31;
        float val = 0.f;
        if (hd < 30 && kk < 180) {
            int ch = seg * 180 + h * 30 + hd;
            val = qkv_w[ch * 180 + kk];
            if (seg == 0) val *= SCALE_Q;
        }
        Whead[idx] = f2bf(val);
    }
    for (int idx = gt; idx < 6 * 96; idx += stride) {
        int h = idx / 96, rr = idx - h * 96;
        int seg = rr >> 5, hd = rr & 31;
        float val = 0.f;
        if (hd < 30) {
            int ch = seg * 180 + h * 30 + hd;
            val = qkv_b[ch];
            if (seg == 0) val *= SCALE_Q;
        }
        bh[idx] = val;
    }
    for (int idx = gt; idx < 192 * 192; idx += stride) {
        int rr = idx / 192, kk = idx - rr * 192;
        Wproj[idx] = (rr < 180 && kk < 180) ? f2bf(proj_w[rr * 180 + kk]) : (short)0;
    }
    for (int idx = gt; idx < 384 * 192; idx += stride) {
        int rr = idx / 192, kk = idx - rr * 192;
        Wfc1[idx] = (rr < 360 && kk < 180) ? f2bf(fc1_w[rr * 180 + kk]) : (short)0;
    }
    for (int idx = gt; idx < 384; idx += stride)
        bfc1[idx] = (idx < 360) ? fc1_b[idx] : 0.f;
    for (int idx = gt; idx < 192 * 384; idx += stride) {
        int rr = idx / 384, kk = idx - rr * 384;
        Wfc2[idx] = (rr < 180 && kk < 360) ? f2bf(fc2_w[rr * 360 + kk]) : (short)0;
    }
    // battn[h][m][n] = bias[h][n][m]  (bf16, transposed so n is contiguous)
    for (int idx = gt; idx < 6 * 64 * 64; idx += stride) {
        int h = idx >> 12, m = (idx >> 6) & 63, n = idx & 63;
        int r1 = n >> 3, c1 = n & 7, r2 = m >> 3, c2 = m & 7;
        int ridx = (r1 - r2 + 7) * 15 + (c1 - c2 + 7);
        battn[idx] = f2bf(rpb[ridx * 6 + h]);
    }
}

// ---------------- fully fused kernel ----------------
// 1 block/window, 384 thr = 6 waves, wave h owns head h.
// LDS 53248 B; 6-wave WG distributes (2,2,1,1) across SIMDs -> a 2nd WG needs
// 4 wave-slots/SIMD, i.e. TOTAL regs (VGPR+AGPR) <= 128 (waves/SIMD halves at
// 64/128/256 total). launch_bounds(384,4) = budget 512/4 = 128. Staging loops
// ks-outer/i-inner keep live set small (acc[4]+1 B-frag, not bw[6]).
//  region A @0     (25600): xln[64][200] -> xout[64][200] -> ylds[64][200] -> mo bf16
//  region B @25600 (27648): patches 6x4608 -> pout bf16 [64][200] -> hid bf16 [64][200]
__global__ __launch_bounds__(384, 4)
void k_fused(const float* __restrict__ x, const float* __restrict__ g1, const float* __restrict__ b1,
             const short* __restrict__ Whead, const float* __restrict__ bh,
             const short* __restrict__ Wproj, const float* __restrict__ projb,
             const short* __restrict__ battn,
             const float* __restrict__ g2, const float* __restrict__ b2,
             const short* __restrict__ Wfc1, const float* __restrict__ bfc1,
             const short* __restrict__ Wfc2, const float* __restrict__ fb2,
             float* __restrict__ out) {
    __shared__ __align__(16) char smem[53248];
    short* xln  = (short*)smem;               // [64][200]
    short* xout = (short*)smem;               // overlays xln (after staging done)
    short* ylds = (short*)smem;               // overlays xout (after proj A-reads)
    short* mo   = (short*)smem;               // overlays ylds (after fc1 done)
    short* regB = (short*)(smem + 25600);
    short* pout = regB;                       // bf16 [64][200]
    short* hid  = regB;                       // bf16 [64][200]

    const int tid = threadIdx.x;
    const int wv = tid >> 6, l = tid & 63, l15 = l & 15, lg = l >> 4;
    short* patch = regB + wv * 2304;          // 4608 B each
    const int wid = blockIdx.x;
    const int b = wid >> 8, win = wid & 255, wi = win >> 4, wj = win & 15;
    const bool edge = (wi == 15) || (wj == 15);
    const f32x4 vzero = {0.f, 0.f, 0.f, 0.f};

    const int t = tid >> 2, sub = tid & 3;
    size_t rowbase = 0;
    if (tid < 256) {
        const int r = t >> 3, c = t & 7;
        const int gi = (wi * 8 + r + 4) & 127, gj = (wj * 8 + c + 4) & 127;
        rowbase = ((size_t)b * 16384 + (size_t)gi * 128 + gj) * 180;
    }
    const float* xrow = x + rowbase;
    float* yrow = out + rowbase;

    // ---- P1: LN1 -> xln (waves 0-3); helpers zero xln pads ----
    if (tid < 256) {
        float4 v[12];
        float s1 = 0.f, s2 = 0.f;
#pragma unroll
        for (int m = 0; m < 12; ++m) {
            int jj = sub + 4 * m;
            if (jj < 45) {
                float4 t4 = *(const float4*)&xrow[4 * jj];
                v[m] = t4;
                s1 += t4.x + t4.y + t4.z + t4.w;
                s2 += t4.x * t4.x + t4.y * t4.y + t4.z * t4.z + t4.w * t4.w;
            }
        }
        s1 += __shfl_xor(s1, 1); s2 += __shfl_xor(s2, 1);
        s1 += __shfl_xor(s1, 2); s2 += __shfl_xor(s2, 2);
        const float mu = s1 * (1.f / 180.f);
        const float rstd = rsqrtf(s2 * (1.f / 180.f) - mu * mu + 1e-5f);
#pragma unroll
        for (int m = 0; m < 12; ++m) {
            int jj = sub + 4 * m;
            if (jj < 45) {
                float4 g4 = *(const float4*)&g1[4 * jj];
                float4 b4 = *(const float4*)&b1[4 * jj];
                s16x4 w;
                w[0] = f2bf((v[m].x - mu) * rstd * g4.x + b4.x);
                w[1] = f2bf((v[m].y - mu) * rstd * g4.y + b4.y);
                w[2] = f2bf((v[m].z - mu) * rstd * g4.z + b4.z);
                w[3] = f2bf((v[m].w - mu) * rstd * g4.w + b4.w);
                *(s16x4*)&xln[t * 200 + 4 * jj] = w;
            }
        }
    } else {
        for (int k = tid - 256; k < 64 * 12; k += 128) {
            int rr = k / 12, cc = k - rr * 12;
            xln[rr * 200 + 180 + cc] = 0;
        }
    }
    __syncthreads();   // B1: xln ready

    // ---- P2: per-wave head staging (Q,K,V through private patch) ----
    const short* Wh = Whead + wv * (96 * 192);
    const float* bhh = bh + wv * 96;

    // ks-outer / i-inner: live set = acc[4] (16) + one B-frag (8), NOT bw[6] (48)
    auto stage = [&](int G, auto&& store) {
#pragma unroll
        for (int jl = 0; jl < 2; ++jl) {
            float bias = bhh[G * 32 + jl * 16 + l15];
            f32x4 acc[4] = {vzero, vzero, vzero, vzero};
#pragma unroll
            for (int ks = 0; ks < 6; ++ks) {
                s16x8 bwk = *(const s16x8*)&Wh[(G * 32 + jl * 16 + l15) * 192 + ks * 32 + lg * 8];
#pragma unroll
                for (int i = 0; i < 4; ++i) {
                    s16x8 afi = *(const s16x8*)&xln[(i * 16 + l15) * 200 + ks * 32 + lg * 8];
                    acc[i] = mfma16(afi, bwk, acc[i]);
                }
            }
#pragma unroll
            for (int i = 0; i < 4; ++i) store(i, jl, acc[i], bias);
        }
    };

    // Q -> patch [64][36]
    stage(0, [&](int i, int jl, f32x4 acc, float bias) {
#pragma unroll
        for (int tt = 0; tt < 4; ++tt)
            patch[(i * 16 + lg * 4 + tt) * 36 + jl * 16 + l15] = f2bf(acc[tt] + bias);
    });
    s16x8 qf[4];
#pragma unroll
    for (int i = 0; i < 4; ++i) qf[i] = ld_b64x2(&patch[(i * 16 + l15) * 36 + lg * 8]);

    // K -> patch [64][36] (reuse)
    stage(1, [&](int i, int jl, f32x4 acc, float bias) {
#pragma unroll
        for (int tt = 0; tt < 4; ++tt)
            patch[(i * 16 + lg * 4 + tt) * 36 + jl * 16 + l15] = f2bf(acc[tt] + bias);
    });
    s16x8 kf[4];
#pragma unroll
    for (int j = 0; j < 4; ++j) kf[j] = ld_b64x2(&patch[(j * 16 + l15) * 36 + lg * 8]);

    // V -> patch transposed [32][72], packed u32 stores
    stage(2, [&](int i, int jl, f32x4 acc, float bias) {
        int hd = jl * 16 + l15;
        int tok0 = i * 16 + lg * 4;
        unsigned int w0 = (unsigned int)(unsigned short)f2bf(acc[0] + bias) |
                          ((unsigned int)(unsigned short)f2bf(acc[1] + bias) << 16);
        unsigned int w1 = (unsigned int)(unsigned short)f2bf(acc[2] + bias) |
                          ((unsigned int)(unsigned short)f2bf(acc[3] + bias) << 16);
        *(unsigned int*)&patch[hd * 72 + tok0] = w0;
        *(unsigned int*)&patch[hd * 72 + tok0 + 2] = w1;
    });
    s16x8 vf[2][2];
#pragma unroll
    for (int j2 = 0; j2 < 2; ++j2)
#pragma unroll
        for (int ksv = 0; ksv < 2; ++ksv)
            vf[j2][ksv] = *(const s16x8*)&patch[(j2 * 16 + l15) * 72 + ksv * 32 + lg * 8];

    __syncthreads();   // B_x: all xln reads done -> xout (region A) writable

    if (wv == 0) {     // zero xout pad cols 180..191
        for (int k = l; k < 64 * 12; k += 64) {
            int rr = k / 12, cc = k - rr * 12;
            xout[rr * 200 + 180 + cc] = 0;
        }
    }

    // ---- attention: scores + softmax + PV, P ping-pong in patch ----
    {
        const short* bb = battn + wv * 4096;
#pragma unroll
        for (int i = 0; i < 4; ++i) {
            f32x4 sc[4];
#pragma unroll
            for (int j = 0; j < 4; ++j) sc[j] = mfma16(qf[i], kf[j], vzero);
            float p[4][4];
#pragma unroll
            for (int j = 0; j < 4; ++j) {
                int m = j * 16 + l15;
                s16x4 bv = *(const s16x4*)&bb[m * 64 + i * 16 + lg * 4];
                int rm = m >> 3, cm = m & 7;
                int cnt_m = (wi == 15 ? ((rm >= 4) ? 2 : 1) : 0) * 3 + (wj == 15 ? ((cm >= 4) ? 2 : 1) : 0);
#pragma unroll
                for (int tt = 0; tt < 4; ++tt) {
                    int n = i * 16 + lg * 4 + tt;
                    float s = sc[j][tt] + bf2f(bv[tt]);
                    if (edge) {
                        int rn = n >> 3, cn = n & 7;
                        int cnt_n = (wi == 15 ? ((rn >= 4) ? 2 : 1) : 0) * 3 + (wj == 15 ? ((cn >= 4) ? 2 : 1) : 0);
                        if (cnt_n != cnt_m) s -= 100.f;
                    }
                    p[j][tt] = s;
                }
            }
            float sm[4];
#pragma unroll
            for (int tt = 0; tt < 4; ++tt) {
                float m0 = fmaxf(fmaxf(p[0][tt], p[1][tt]), fmaxf(p[2][tt], p[3][tt]));
                m0 = fmaxf(m0, __shfl_xor(m0, 1));
                m0 = fmaxf(m0, __shfl_xor(m0, 2));
                m0 = fmaxf(m0, __shfl_xor(m0, 4));
                m0 = fmaxf(m0, __shfl_xor(m0, 8));
                float s0 = 0.f;
#pragma unroll
                for (int j = 0; j < 4; ++j) { float e = __expf(p[j][tt] - m0); p[j][tt] = e; s0 += e; }
                s0 += __shfl_xor(s0, 1); s0 += __shfl_xor(s0, 2);
                s0 += __shfl_xor(s0, 4); s0 += __shfl_xor(s0, 8);
                sm[tt] = __builtin_amdgcn_rcpf(s0);
            }
            short* pb = patch + (i & 1) * 1152;   // ping-pong [16][72]
#pragma unroll
            for (int j = 0; j < 4; ++j)
#pragma unroll
                for (int tt = 0; tt < 4; ++tt)
                    pb[(lg * 4 + tt) * 72 + j * 16 + l15] = f2bf(p[j][tt] * sm[tt]);
            s16x8 pa0 = *(const s16x8*)&pb[l15 * 72 + lg * 8];
            s16x8 pa1 = *(const s16x8*)&pb[l15 * 72 + 32 + lg * 8];
            f32x4 ov0 = mfma16(pa0, vf[0][0], vzero);
            ov0 = mfma16(pa1, vf[0][1], ov0);
            f32x4 ov1 = mfma16(pa0, vf[1][0], vzero);
            ov1 = mfma16(pa1, vf[1][1], ov1);
            // xout rows i*16.., cols wv*30 + hd
#pragma unroll
            for (int tt = 0; tt < 4; ++tt)
                xout[(i * 16 + lg * 4 + tt) * 200 + wv * 30 + l15] = f2bf(ov0[tt]);
            if (l15 < 14) {
#pragma unroll
                for (int tt = 0; tt < 4; ++tt)
                    xout[(i * 16 + lg * 4 + tt) * 200 + wv * 30 + 16 + l15] = f2bf(ov1[tt]);
            }
        }
    }
    __syncthreads();   // B3: xout complete, patches dead

    // ---- P3: proj GEMM -> pout bf16 (region B) ----
    {
#pragma unroll
        for (int jl = 0; jl < 2; ++jl) {
            int cch = wv * 32 + jl * 16 + l15;
            float pbv = (cch < 180) ? projb[cch] : 0.f;
            f32x4 acc[4] = {vzero, vzero, vzero, vzero};
#pragma unroll
            for (int ks = 0; ks < 6; ++ks) {
                s16x8 bwk = *(const s16x8*)&Wproj[(wv * 32 + jl * 16 + l15) * 192 + ks * 32 + lg * 8];
#pragma unroll
                for (int i = 0; i < 4; ++i) {
                    s16x8 afi = *(const s16x8*)&xout[(i * 16 + l15) * 200 + ks * 32 + lg * 8];
                    acc[i] = mfma16(afi, bwk, acc[i]);
                }
            }
            if (cch < 180) {
#pragma unroll
                for (int i = 0; i < 4; ++i)
#pragma unroll
                    for (int tt = 0; tt < 4; ++tt)
                        pout[(i * 16 + lg * 4 + tt) * 200 + cch] = f2bf(acc[i][tt] + pbv);
            }
        }
    }
    __syncthreads();   // B4: pout ready, xout dead

    // ---- P4: y = x + pout -> d_out (f32) ; LN2 -> ylds ----
    if (tid < 256) {
        float4 yv[12];
        float s1 = 0.f, s2 = 0.f;
#pragma unroll
        for (int m = 0; m < 12; ++m) {
            int jj = sub + 4 * m;
            if (jj < 45) {
                float4 x4 = *(const float4*)&xrow[4 * jj];
                s16x4 pv = *(const s16x4*)&pout[t * 200 + 4 * jj];
                float4 y4;
                y4.x = x4.x + bf2f(pv[0]); y4.y = x4.y + bf2f(pv[1]);
                y4.z = x4.z + bf2f(pv[2]); y4.w = x4.w + bf2f(pv[3]);
                yv[m] = y4;
                *(float4*)&yrow[4 * jj] = y4;
                s1 += y4.x + y4.y + y4.z + y4.w;
                s2 += y4.x * y4.x + y4.y * y4.y + y4.z * y4.z + y4.w * y4.w;
            }
        }
        s1 += __shfl_xor(s1, 1); s2 += __shfl_xor(s2, 1);
        s1 += __shfl_xor(s1, 2); s2 += __shfl_xor(s2, 2);
        const float mu = s1 * (1.f / 180.f);
        const float rstd = rsqrtf(s2 * (1.f / 180.f) - mu * mu + 1e-5f);
#pragma unroll
        for (int m = 0; m < 12; ++m) {
            int jj = sub + 4 * m;
            if (jj < 45) {
                float4 g4 = *(const float4*)&g2[4 * jj];
                float4 b4 = *(const float4*)&b2[4 * jj];
                s16x4 w;
                w[0] = f2bf((yv[m].x - mu) * rstd * g4.x + b4.x);
                w[1] = f2bf((yv[m].y - mu) * rstd * g4.y + b4.y);
                w[2] = f2bf((yv[m].z - mu) * rstd * g4.z + b4.z);
                w[3] = f2bf((yv[m].w - mu) * rstd * g4.w + b4.w);
                *(s16x4*)&ylds[t * 200 + 4 * jj] = w;
            }
        }
    } else {
        for (int k = tid - 256; k < 64 * 12; k += 128) {
            int rr = k / 12, cc = k - rr * 12;
            ylds[rr * 200 + 180 + cc] = 0;
        }
    }
    __syncthreads();   // B5: ylds ready, pout dead

    // ---- P5: MLP (fc1+GELU per K-half, fc2 accumulated) ----
    f32x4 acc3[2][4];
#pragma unroll
    for (int jl = 0; jl < 2; ++jl)
#pragma unroll
        for (int i = 0; i < 4; ++i) acc3[jl][i] = vzero;

#pragma unroll
    for (int kh = 0; kh < 2; ++kh) {
#pragma unroll
        for (int jl = 0; jl < 2; ++jl) {
            int cl = (wv * 2 + jl) * 16 + l15;
            float bv = bfc1[kh * 192 + cl];
            f32x4 acc[4] = {vzero, vzero, vzero, vzero};
#pragma unroll
            for (int ks = 0; ks < 6; ++ks) {
                s16x8 bwk = *(const s16x8*)&Wfc1[((kh * 12 + wv * 2 + jl) * 16 + l15) * 192 + ks * 32 + lg * 8];
#pragma unroll
                for (int i = 0; i < 4; ++i) {
                    s16x8 ai = *(const s16x8*)&ylds[(i * 16 + l15) * 200 + ks * 32 + lg * 8];
                    acc[i] = mfma16(ai, bwk, acc[i]);
                }
            }
#pragma unroll
            for (int i = 0; i < 4; ++i)
#pragma unroll
                for (int tt = 0; tt < 4; ++tt) {
                    float v = acc[i][tt] + bv;
                    // gelu(v) ~= v * sigmoid(1.5957691*(v + 0.044715 v^3)); max err ~3e-4
                    float u = v * (1.f + 0.044715f * v * v);
                    float e = __expf(-1.5957691216f * u);
                    float gl = v * __builtin_amdgcn_rcpf(1.f + e);
                    hid[(i * 16 + lg * 4 + tt) * 200 + cl] = f2bf(gl);
                }
        }
        __syncthreads();   // hid(kh) ready
#pragma unroll
        for (int ks = 0; ks < 6; ++ks) {
            s16x8 a[4];
#pragma unroll
            for (int i = 0; i < 4; ++i)
                a[i] = *(const s16x8*)&hid[(i * 16 + l15) * 200 + ks * 32 + lg * 8];
#pragma unroll
            for (int jl = 0; jl < 2; ++jl) {
                s16x8 bw2 = *(const s16x8*)&Wfc2[((wv * 2 + jl) * 16 + l15) * 384 + kh * 192 + ks * 32 + lg * 8];
#pragma unroll
                for (int i = 0; i < 4; ++i) acc3[jl][i] = mfma16(a[i], bw2, acc3[jl][i]);
            }
        }
        __syncthreads();   // hid consumed
    }

    // ---- fc2 out -> mo bf16 (region A; ylds dead) ----
#pragma unroll
    for (int jl = 0; jl < 2; ++jl) {
        int cch = (wv * 2 + jl) * 16 + l15;
        if (cch < 180) {
            float bv = fb2[cch];
#pragma unroll
            for (int i = 0; i < 4; ++i)
#pragma unroll
                for (int tt = 0; tt < 4; ++tt)
                    mo[(i * 16 + lg * 4 + tt) * 200 + cch] = f2bf(acc3[jl][i][tt] + bv);
        }
    }
    __syncthreads();   // B6: mo ready

    // ---- final: out = y + mlp ----
    if (tid < 256) {
#pragma unroll
        for (int m = 0; m < 12; ++m) {
            int jj = sub + 4 * m;
            if (jj < 45) {
                float4 y4 = *(const float4*)&yrow[4 * jj];
                s16x4 mv = *(const s16x4*)&mo[t * 200 + 4 * jj];
                float4 o;
                o.x = y4.x + bf2f(mv[0]); o.y = y4.y + bf2f(mv[1]);
                o.z = y4.z + bf2f(mv[2]); o.w = y4.w + bf2f(mv[3]);
                *(float4*)&yrow[4 * jj] = o;
            }
        }
    }
}

extern "C" void kernel_launch(void* const* d_in, const int* in_sizes, int n_in,
                              void* d_out, int out_size, void* d_ws, size_t ws_size,
                              hipStream_t stream) {
    (void)in_sizes; (void)n_in; (void)out_size; (void)ws_size;
    const float* x      = (const float*)d_in[0];
    const float* ln1g   = (const float*)d_in[1];
    const float* ln1b   = (const float*)d_in[2];
    const float* qkv_w  = (const float*)d_in[3];
    const float* qkv_b  = (const float*)d_in[4];
    const float* proj_w = (const float*)d_in[5];
    const float* proj_b = (const float*)d_in[6];
    const float* rpb    = (const float*)d_in[7];
    const float* ln2g   = (const float*)d_in[8];
    const float* ln2b   = (const float*)d_in[9];
    const float* fc1_w  = (const float*)d_in[10];
    const float* fc1_b  = (const float*)d_in[11];
    const float* fc2_w  = (const float*)d_in[12];
    const float* fc2_b  = (const float*)d_in[13];
    float* out = (float*)d_out;

    char* ws = (char*)d_ws;
    short* Whead = (short*)(ws + 0);
    short* Wproj = (short*)(ws + 221184);
    short* Wfc1  = (short*)(ws + 294912);
    short* Wfc2  = (short*)(ws + 442368);
    short* battn = (short*)(ws + 589824);
    float* bhp   = (float*)(ws + 638976);
    float* bfc1p = (float*)(ws + 641280);

    k_prep<<<256, 256, 0, stream>>>(qkv_w, qkv_b, proj_w, fc1_w, fc1_b, fc2_w, rpb,
                                    Whead, Wproj, Wfc1, Wfc2, battn, bhp, bfc1p);
    k_fused<<<4096, 384, 0, stream>>>(x, ln1g, ln1b, Whead, bhp, Wproj, proj_b, battn,
                                      ln2g, ln2b, Wfc1, bfc1p, Wfc2, fc2_b, out);
}